// Round 1
// baseline (844.546 us; speedup 1.0000x reference)
//
#include <hip/hip_runtime.h>
#include <stdint.h>

// ---------------------------------------------------------------------------
// Problem constants: B=32, N=4096, D=256, S=8 slots, H_MLP=512, 3 iterations.
// ---------------------------------------------------------------------------

typedef __attribute__((ext_vector_type(8))) short bf16x8;
typedef __attribute__((ext_vector_type(4))) float f32x4;

__device__ __forceinline__ float bf2f_lo(uint32_t u) {
    union { uint32_t u; float f; } v; v.u = u << 16; return v.f;
}
__device__ __forceinline__ float bf2f_hi(uint32_t u) {
    union { uint32_t u; float f; } v; v.u = u & 0xffff0000u; return v.f;
}
__device__ __forceinline__ unsigned short f2bf(float f) {
    union { float f; uint32_t u; } v; v.f = f;
    uint32_t r = (v.u + 0x7fffu + ((v.u >> 16) & 1u)) >> 16;
    return (unsigned short)r;
}

__device__ __forceinline__ void gld_lds16(const void* g, void* l) {
    __builtin_amdgcn_global_load_lds(
        (__attribute__((address_space(1))) unsigned int*)g,
        (__attribute__((address_space(3))) unsigned int*)l,
        16, 0, 0);
}

// ---------------------------------------------------------------------------
// Kernel 1: LayerNorm over inputs [B*N, 256] -> bf16.  One row per wave.
// ---------------------------------------------------------------------------
__global__ __launch_bounds__(256) void ln_in_k(const float* __restrict__ in,
                                               const float* __restrict__ gg,
                                               const float* __restrict__ bb,
                                               unsigned short* __restrict__ xo) {
    int wave = threadIdx.x >> 6, lane = threadIdx.x & 63;
    size_t row = (size_t)blockIdx.x * 4 + wave;
    const float4 x = *(const float4*)(in + row * 256 + lane * 4);
    float s  = x.x + x.y + x.z + x.w;
    float sq = x.x * x.x + x.y * x.y + x.z * x.z + x.w * x.w;
#pragma unroll
    for (int off = 32; off > 0; off >>= 1) {
        s  += __shfl_xor(s,  off, 64);
        sq += __shfl_xor(sq, off, 64);
    }
    float mean = s * (1.0f / 256.0f);
    float var  = sq * (1.0f / 256.0f) - mean * mean;
    float rstd = rsqrtf(var + 1e-3f);
    float4 g4 = *(const float4*)(gg + lane * 4);
    float4 b4 = *(const float4*)(bb + lane * 4);
    unsigned short h0 = f2bf((x.x - mean) * rstd * g4.x + b4.x);
    unsigned short h1 = f2bf((x.y - mean) * rstd * g4.y + b4.y);
    unsigned short h2 = f2bf((x.z - mean) * rstd * g4.z + b4.z);
    unsigned short h3 = f2bf((x.w - mean) * rstd * g4.w + b4.w);
    uint2 o;
    o.x = (uint32_t)h0 | ((uint32_t)h1 << 16);
    o.y = (uint32_t)h2 | ((uint32_t)h3 << 16);
    *(uint2*)(xo + row * 256 + lane * 4) = o;
}

// ---------------------------------------------------------------------------
// Kernel 2: convert Wk,Wv (fp32 [256,256]) to one bf16 [512,256]; pack biases.
// ---------------------------------------------------------------------------
__global__ __launch_bounds__(256) void cvt_w_k(const float* __restrict__ Wk,
                                               const float* __restrict__ bk,
                                               const float* __restrict__ Wv,
                                               const float* __restrict__ bv,
                                               unsigned short* __restrict__ Wkv,
                                               float* __restrict__ bkv) {
    int i = blockIdx.x * 256 + threadIdx.x;  // 0..131071
    Wkv[i] = (i < 65536) ? f2bf(Wk[i]) : f2bf(Wv[i - 65536]);
    if (i < 256) bkv[i] = bk[i];
    else if (i < 512) bkv[i] = bv[i - 256];
}

// ---------------------------------------------------------------------------
// Kernel 3: bf16 MFMA GEMM  C[131072,512] = X[131072,256] @ Wkv^T, split K|V.
// 128x128 tile, BK=64, 4 waves each computing 64x64 (4x4 tiles of 16x16x32).
// m97 structure: global_load_lds width=16 staging, ds_read_b128 fragments.
// ---------------------------------------------------------------------------
__global__ __launch_bounds__(256) void gemm_kv(const unsigned short* __restrict__ X,
                                               const unsigned short* __restrict__ W,
                                               const float* __restrict__ bkv,
                                               unsigned short* __restrict__ Ko,
                                               unsigned short* __restrict__ Vo) {
    __shared__ __align__(16) unsigned short As[128 * 64];
    __shared__ __align__(16) unsigned short Bs[128 * 64];
    int t = threadIdx.x;
    int wave = t >> 6, lane = t & 63;
    int wr = wave >> 1, wc = wave & 1;
    int m0 = blockIdx.x * 128;
    int j0 = blockIdx.y * 128;

    f32x4 acc[4][4];
#pragma unroll
    for (int i = 0; i < 4; ++i)
#pragma unroll
        for (int j = 0; j < 4; ++j)
#pragma unroll
            for (int r = 0; r < 4; ++r) acc[i][j][r] = 0.f;

    int row8 = lane >> 3;          // 0..7: sub-row within 8-row group
    int c8   = (lane & 7) * 8;     // element offset within 64-wide K slab

    for (int kb = 0; kb < 4; ++kb) {
        int k0 = kb * 64;
#pragma unroll
        for (int i = 0; i < 4; ++i) {
            int rbase = wave * 32 + i * 8;  // wave-uniform LDS base row
            gld_lds16(X + (size_t)(m0 + rbase + row8) * 256 + k0 + c8, &As[rbase * 64]);
            gld_lds16(W + (size_t)(j0 + rbase + row8) * 256 + k0 + c8, &Bs[rbase * 64]);
        }
        __syncthreads();
#pragma unroll
        for (int kk = 0; kk < 64; kk += 32) {
            int koff = kk + (lane >> 4) * 8;
            bf16x8 af[4], bf[4];
#pragma unroll
            for (int ti = 0; ti < 4; ++ti)
                af[ti] = *(const bf16x8*)&As[(wr * 64 + ti * 16 + (lane & 15)) * 64 + koff];
#pragma unroll
            for (int tj = 0; tj < 4; ++tj)
                bf[tj] = *(const bf16x8*)&Bs[(wc * 64 + tj * 16 + (lane & 15)) * 64 + koff];
#pragma unroll
            for (int ti = 0; ti < 4; ++ti)
#pragma unroll
                for (int tj = 0; tj < 4; ++tj)
                    acc[ti][tj] = __builtin_amdgcn_mfma_f32_16x16x32_bf16(
                        af[ti], bf[tj], acc[ti][tj], 0, 0, 0);
        }
        __syncthreads();
    }

    bool isK = (j0 < 256);  // uniform per block (jb 0,1 -> K; 2,3 -> V)
    unsigned short* base = isK ? Ko : Vo;
    int csub = isK ? 0 : 256;
#pragma unroll
    for (int ti = 0; ti < 4; ++ti) {
#pragma unroll
        for (int tj = 0; tj < 4; ++tj) {
            int col = j0 + wc * 64 + tj * 16 + (lane & 15);
            float bias = bkv[col];
            int outc = col - csub;
#pragma unroll
            for (int r = 0; r < 4; ++r) {
                int row = m0 + wr * 64 + ti * 16 + (lane >> 4) * 4 + r;
                base[(size_t)row * 256 + outc] = f2bf(acc[ti][tj][r] + bias);
            }
        }
    }
}

// ---------------------------------------------------------------------------
// Row LayerNorm for 256 slot-rows of width 256 (block per row).
// ---------------------------------------------------------------------------
__global__ __launch_bounds__(256) void ln_rows_k(const float* __restrict__ src,
                                                 const float* __restrict__ gg,
                                                 const float* __restrict__ bb,
                                                 float* __restrict__ dst) {
    __shared__ float rs[4], rq[4];
    int row = blockIdx.x, t = threadIdx.x;
    float x = src[(size_t)row * 256 + t];
    float s = x, sq = x * x;
#pragma unroll
    for (int off = 32; off > 0; off >>= 1) {
        s  += __shfl_xor(s,  off, 64);
        sq += __shfl_xor(sq, off, 64);
    }
    if ((t & 63) == 0) { rs[t >> 6] = s; rq[t >> 6] = sq; }
    __syncthreads();
    s  = rs[0] + rs[1] + rs[2] + rs[3];
    sq = rq[0] + rq[1] + rq[2] + rq[3];
    float mean = s * (1.0f / 256.0f);
    float var  = sq * (1.0f / 256.0f) - mean * mean;
    float rstd = rsqrtf(var + 1e-3f);
    dst[(size_t)row * 256 + t] = (x - mean) * rstd * gg[t] + bb[t];
}

// ---------------------------------------------------------------------------
// Small GEMM over the 8 slot rows of one batch: out[b*8+s][jj] =
//   sum_k src[b*8+s][k] * W[jj][k] (+bias, optional /row_div, relu, +resid).
// Block = one batch (8 rows staged in LDS, full weight reuse across rows).
// blockIdx.y selects a 256-wide slab of output features.
// ---------------------------------------------------------------------------
template <int IN_DIM>
__global__ __launch_bounds__(256) void small_gemm8(const float* __restrict__ src,
                                                   const float* __restrict__ W,
                                                   const float* __restrict__ bias,
                                                   float* __restrict__ out,
                                                   int out_stride,
                                                   const float* __restrict__ row_div,
                                                   const float* __restrict__ resid,
                                                   int relu) {
    __shared__ __align__(16) float xs[8 * IN_DIM];
    int b = blockIdx.x, t = threadIdx.x;
    for (int i = t; i < 8 * IN_DIM; i += 256) {
        int s = i / IN_DIM;
        float v = src[(size_t)b * 8 * IN_DIM + i];
        if (row_div) v *= (1.0f / row_div[b * 8 + s]);
        xs[i] = v;
    }
    __syncthreads();
    int jj = blockIdx.y * 256 + t;
    const float4* w4 = (const float4*)(W + (size_t)jj * IN_DIM);
    float acc[8];
#pragma unroll
    for (int s = 0; s < 8; ++s) acc[s] = 0.f;
#pragma unroll 4
    for (int k = 0; k < IN_DIM / 4; ++k) {
        float4 w = w4[k];
#pragma unroll
        for (int s = 0; s < 8; ++s) {
            float4 x = *(const float4*)(xs + s * IN_DIM + k * 4);
            acc[s] += w.x * x.x + w.y * x.y + w.z * x.z + w.w * x.w;
        }
    }
    float bs = bias[jj];
#pragma unroll
    for (int s = 0; s < 8; ++s) {
        float v = acc[s] + bs;
        if (relu) v = fmaxf(v, 0.f);
        size_t oi = ((size_t)b * 8 + s) * out_stride + jj;
        if (resid) v += resid[oi];
        out[oi] = v;
    }
}

// ---------------------------------------------------------------------------
// dots + softmax over slots + per-(b,s) partial sums.  Block = (b, 256 n's).
// Thread owns one n: 8 dot-products of length 256 against LDS-staged q.
// ---------------------------------------------------------------------------
__global__ __launch_bounds__(256) void dots_attn_k(const float* __restrict__ q,
                                                   const unsigned short* __restrict__ K,
                                                   float* __restrict__ attn,
                                                   float* __restrict__ sums) {
    __shared__ __align__(16) float qs[2048];
    __shared__ float ssum[8];
    int b = blockIdx.x, nb = blockIdx.y, t = threadIdx.x;
    for (int i = t; i < 2048; i += 256) qs[i] = q[(size_t)b * 2048 + i];
    if (t < 8) ssum[t] = 0.f;
    __syncthreads();
    int n = nb * 256 + t;
    const uint4* kp = (const uint4*)(K + ((size_t)b * 4096 + n) * 256);
    float acc[8];
#pragma unroll
    for (int s = 0; s < 8; ++s) acc[s] = 0.f;
    for (int c = 0; c < 32; ++c) {
        uint4 kv = kp[c];
        float f0 = bf2f_lo(kv.x), f1 = bf2f_hi(kv.x);
        float f2 = bf2f_lo(kv.y), f3 = bf2f_hi(kv.y);
        float f4 = bf2f_lo(kv.z), f5 = bf2f_hi(kv.z);
        float f6 = bf2f_lo(kv.w), f7 = bf2f_hi(kv.w);
#pragma unroll
        for (int s = 0; s < 8; ++s) {
            const float4* q4 = (const float4*)(qs + s * 256 + c * 8);
            float4 a = q4[0], bb = q4[1];
            acc[s] += f0 * a.x + f1 * a.y + f2 * a.z + f3 * a.w +
                      f4 * bb.x + f5 * bb.y + f6 * bb.z + f7 * bb.w;
        }
    }
    float m = -1e30f;
#pragma unroll
    for (int s = 0; s < 8; ++s) { acc[s] *= 0.0625f; m = fmaxf(m, acc[s]); }
    float e[8], sum = 0.f;
#pragma unroll
    for (int s = 0; s < 8; ++s) { e[s] = __expf(acc[s] - m); sum += e[s]; }
    float inv = 1.0f / sum;
#pragma unroll
    for (int s = 0; s < 8; ++s) {
        float a = e[s] * inv + 1e-8f;
        attn[((size_t)b * 8 + s) * 4096 + n] = a;
        float w = a;
#pragma unroll
        for (int off = 32; off > 0; off >>= 1) w += __shfl_xor(w, off, 64);
        if ((t & 63) == 0) atomicAdd(&ssum[s], w);
    }
    __syncthreads();
    if (t < 8) atomicAdd(&sums[b * 8 + t], ssum[t]);
}

// ---------------------------------------------------------------------------
// updates[b,s,d] += sum_n attn[b,s,n] * v[b,n,d]   (n split across blockIdx.z,
// atomic accumulate; normalization by sums happens at GRU staging).
// ---------------------------------------------------------------------------
__global__ __launch_bounds__(256) void upd_k(const float* __restrict__ attn,
                                             const unsigned short* __restrict__ V,
                                             float* __restrict__ upd) {
    int b = blockIdx.x, dc = blockIdx.y, nz = blockIdx.z;
    int g = threadIdx.x >> 6, l = threadIdx.x & 63;
    int d = dc * 128 + l * 2;
    int s0 = g * 2;
    const float* a0 = attn + ((size_t)b * 8 + s0) * 4096;
    const float* a1 = a0 + 4096;
    const unsigned short* vbase = V + (size_t)b * 4096 * 256 + d;
    float acc00 = 0, acc01 = 0, acc10 = 0, acc11 = 0;
    int nstart = nz * 512;
    for (int n = nstart; n < nstart + 512; ++n) {
        uint32_t vv = *(const uint32_t*)(vbase + (size_t)n * 256);
        float v0 = bf2f_lo(vv), v1 = bf2f_hi(vv);
        float x0 = a0[n], x1 = a1[n];
        acc00 += x0 * v0; acc01 += x0 * v1;
        acc10 += x1 * v0; acc11 += x1 * v1;
    }
    float* u0 = upd + ((size_t)b * 8 + s0) * 256 + d;
    float* u1 = u0 + 256;
    atomicAdd(u0, acc00); atomicAdd(u0 + 1, acc01);
    atomicAdd(u1, acc10); atomicAdd(u1 + 1, acc11);
}

// ---------------------------------------------------------------------------
// GRU combine: r,z,n gates from gi/gh [256 rows x 768], h from slots_prev.
// ---------------------------------------------------------------------------
__global__ __launch_bounds__(256) void gru_combine_k(const float* __restrict__ gi,
                                                     const float* __restrict__ gh,
                                                     const float* __restrict__ hprev,
                                                     float* __restrict__ out) {
    int row = blockIdx.x, j = threadIdx.x;
    const float* gir = gi + (size_t)row * 768;
    const float* ghr = gh + (size_t)row * 768;
    float r  = 1.0f / (1.0f + __expf(-(gir[j] + ghr[j])));
    float z  = 1.0f / (1.0f + __expf(-(gir[256 + j] + ghr[256 + j])));
    float nn = tanhf(gir[512 + j] + r * ghr[512 + j]);
    float h  = hprev[(size_t)row * 256 + j];
    out[(size_t)row * 256 + j] = (1.0f - z) * nn + z * h;
}

// ---------------------------------------------------------------------------
// Host: orchestrate.  B=32,N=4096,D=256,S=8,H=512, 3 iterations (step==0).
// ---------------------------------------------------------------------------
extern "C" void kernel_launch(void* const* d_in, const int* in_sizes, int n_in,
                              void* d_out, int out_size, void* d_ws, size_t ws_size,
                              hipStream_t stream) {
    const float* inputs    = (const float*)d_in[0];
    const float* slots_in  = (const float*)d_in[1];
    const float* ln_in_g   = (const float*)d_in[3];
    const float* ln_in_b   = (const float*)d_in[4];
    const float* ln_slot_g = (const float*)d_in[5];
    const float* ln_slot_b = (const float*)d_in[6];
    const float* ln_mlp_g  = (const float*)d_in[7];
    const float* ln_mlp_b  = (const float*)d_in[8];
    const float* Wq   = (const float*)d_in[9];
    const float* bq   = (const float*)d_in[10];
    const float* Wk   = (const float*)d_in[11];
    const float* bk   = (const float*)d_in[12];
    const float* Wv   = (const float*)d_in[13];
    const float* bv   = (const float*)d_in[14];
    const float* W_ih = (const float*)d_in[15];
    const float* b_ih = (const float*)d_in[16];
    const float* W_hh = (const float*)d_in[17];
    const float* b_hh = (const float*)d_in[18];
    const float* W1   = (const float*)d_in[19];
    const float* b1   = (const float*)d_in[20];
    const float* W2   = (const float*)d_in[21];
    const float* b2   = (const float*)d_in[22];

    char* p = (char*)d_ws;
    size_t off = 0;
    auto take = [&](size_t bytes) -> char* {
        char* r = p + off;
        off += (bytes + 255) & ~(size_t)255;
        return r;
    };
    unsigned short* xbf = (unsigned short*)take((size_t)131072 * 256 * 2);
    unsigned short* Kb  = (unsigned short*)take((size_t)131072 * 256 * 2);
    unsigned short* Vb  = (unsigned short*)take((size_t)131072 * 256 * 2);
    unsigned short* Wkv = (unsigned short*)take((size_t)512 * 256 * 2);
    float* bkv    = (float*)take(512 * 4);
    float* qbuf   = (float*)take(256 * 256 * 4);
    float* attn   = (float*)take((size_t)32 * 8 * 4096 * 4);
    float* sums   = (float*)take(256 * 4);
    float* upd    = (float*)take(256 * 256 * 4);
    float* gi     = (float*)take(256 * 768 * 4);
    float* gh     = (float*)take(256 * 768 * 4);
    float* snorm  = (float*)take(256 * 256 * 4);
    float* hidden = (float*)take(256 * 512 * 4);
    float* s0     = (float*)take(256 * 256 * 4);
    float* s1     = (float*)take(256 * 256 * 4);
    float* s2     = (float*)take(256 * 256 * 4);
    float* s3     = (float*)take(256 * 256 * 4);

    // Phase 1: LN(inputs) -> bf16; weights -> bf16; K/V GEMM.
    ln_in_k<<<32768, 256, 0, stream>>>(inputs, ln_in_g, ln_in_b, xbf);
    cvt_w_k<<<512, 256, 0, stream>>>(Wk, bk, Wv, bv, Wkv, bkv);
    gemm_kv<<<dim3(1024, 4), 256, 0, stream>>>(xbf, Wkv, bkv, Kb, Vb);
    hipMemcpyAsync(s0, slots_in, 256 * 256 * 4, hipMemcpyDeviceToDevice, stream);

    float* cur = s0;
    float* nxt[3] = {s2, s3, (float*)d_out};
    for (int it = 0; it < 3; ++it) {
        ln_rows_k<<<256, 256, 0, stream>>>(cur, ln_slot_g, ln_slot_b, snorm);
        small_gemm8<256><<<dim3(32, 1), 256, 0, stream>>>(snorm, Wq, bq, qbuf, 256,
                                                          nullptr, nullptr, 0);
        hipMemsetAsync(sums, 0, 256 * 4, stream);
        dots_attn_k<<<dim3(32, 16), 256, 0, stream>>>(qbuf, Kb, attn, sums);
        hipMemsetAsync(upd, 0, 256 * 256 * 4, stream);
        upd_k<<<dim3(32, 2, 8), 256, 0, stream>>>(attn, Vb, upd);
        // GRU gates: gi = (updates/sums) @ W_ih^T + b_ih ; gh = slots @ W_hh^T + b_hh
        small_gemm8<256><<<dim3(32, 3), 256, 0, stream>>>(upd, W_ih, b_ih, gi, 768,
                                                          sums, nullptr, 0);
        small_gemm8<256><<<dim3(32, 3), 256, 0, stream>>>(cur, W_hh, b_hh, gh, 768,
                                                          nullptr, nullptr, 0);
        gru_combine_k<<<256, 256, 0, stream>>>(gi, gh, cur, s1);
        // MLP residual
        ln_rows_k<<<256, 256, 0, stream>>>(s1, ln_mlp_g, ln_mlp_b, snorm);
        small_gemm8<256><<<dim3(32, 2), 256, 0, stream>>>(snorm, W1, b1, hidden, 512,
                                                          nullptr, nullptr, 1);
        small_gemm8<512><<<dim3(32, 1), 256, 0, stream>>>(hidden, W2, b2, nxt[it], 256,
                                                          nullptr, s1, 0);
        cur = nxt[it];
    }
    (void)in_sizes; (void)n_in; (void)out_size; (void)ws_size;
}

// Round 2
// 682.978 us; speedup vs baseline: 1.2366x; 1.2366x over previous
//
#include <hip/hip_runtime.h>
#include <stdint.h>

// B=32, N=4096, D=256, S=8, H_MLP=512, 3 iterations.

typedef __attribute__((ext_vector_type(8))) short bf16x8;
typedef __attribute__((ext_vector_type(4))) float f32x4;

__device__ __forceinline__ float bf2f_lo(uint32_t u) {
    union { uint32_t u; float f; } v; v.u = u << 16; return v.f;
}
__device__ __forceinline__ float bf2f_hi(uint32_t u) {
    union { uint32_t u; float f; } v; v.u = u & 0xffff0000u; return v.f;
}
__device__ __forceinline__ unsigned short f2bf(float f) {
    union { float f; uint32_t u; } v; v.f = f;
    return (unsigned short)((v.u + 0x7fffu + ((v.u >> 16) & 1u)) >> 16);
}
__device__ __forceinline__ void gld_lds16(const void* g, void* l) {
    __builtin_amdgcn_global_load_lds(
        (__attribute__((address_space(1))) unsigned int*)g,
        (__attribute__((address_space(3))) unsigned int*)l, 16, 0, 0);
}
__device__ __forceinline__ void unpack8(uint4 v, float* f) {
    f[0] = bf2f_lo(v.x); f[1] = bf2f_hi(v.x); f[2] = bf2f_lo(v.y); f[3] = bf2f_hi(v.y);
    f[4] = bf2f_lo(v.z); f[5] = bf2f_hi(v.z); f[6] = bf2f_lo(v.w); f[7] = bf2f_hi(v.w);
}
__device__ __forceinline__ float sigf(float x) { return 1.0f / (1.0f + __expf(-x)); }

// ---------------------------------------------------------------------------
// LayerNorm inputs [131072,256] -> bf16. One row per wave.
// ---------------------------------------------------------------------------
__global__ __launch_bounds__(256) void ln_in_k(const float* __restrict__ in,
                                               const float* __restrict__ gg,
                                               const float* __restrict__ bb,
                                               unsigned short* __restrict__ xo) {
    int wave = threadIdx.x >> 6, lane = threadIdx.x & 63;
    size_t row = (size_t)blockIdx.x * 4 + wave;
    const float4 x = *(const float4*)(in + row * 256 + lane * 4);
    float s  = x.x + x.y + x.z + x.w;
    float sq = x.x * x.x + x.y * x.y + x.z * x.z + x.w * x.w;
#pragma unroll
    for (int off = 32; off > 0; off >>= 1) {
        s  += __shfl_xor(s,  off, 64);
        sq += __shfl_xor(sq, off, 64);
    }
    float mean = s * (1.0f / 256.0f);
    float rstd = rsqrtf(sq * (1.0f / 256.0f) - mean * mean + 1e-3f);
    float4 g4 = *(const float4*)(gg + lane * 4);
    float4 b4 = *(const float4*)(bb + lane * 4);
    uint2 o;
    o.x = (uint32_t)f2bf((x.x - mean) * rstd * g4.x + b4.x) |
          ((uint32_t)f2bf((x.y - mean) * rstd * g4.y + b4.y) << 16);
    o.y = (uint32_t)f2bf((x.z - mean) * rstd * g4.z + b4.z) |
          ((uint32_t)f2bf((x.w - mean) * rstd * g4.w + b4.w) << 16);
    *(uint2*)(xo + row * 256 + lane * 4) = o;
}

// ---------------------------------------------------------------------------
// Convert all weights to bf16, pack biases. i covers 851968 ushort elems.
// ---------------------------------------------------------------------------
__global__ __launch_bounds__(256) void cvt_all(
    const float* __restrict__ Wk, const float* __restrict__ Wv,
    const float* __restrict__ W_ih, const float* __restrict__ W_hh,
    const float* __restrict__ W1, const float* __restrict__ W2,
    const float* __restrict__ Wq,
    const float* __restrict__ bk, const float* __restrict__ bv,
    const float* __restrict__ b_ih, const float* __restrict__ b_hh,
    unsigned short* __restrict__ Wkv, unsigned short* __restrict__ Wg,
    unsigned short* __restrict__ W1b, unsigned short* __restrict__ W2b,
    unsigned short* __restrict__ Wqb,
    float* __restrict__ bkv, float* __restrict__ bg) {
    int i = blockIdx.x * 256 + threadIdx.x;
    if (i < 131072)      Wkv[i] = f2bf(i < 65536 ? Wk[i] : Wv[i - 65536]);
    else if (i < 524288) { int j = i - 131072; Wg[j] = f2bf(j < 196608 ? W_ih[j] : W_hh[j - 196608]); }
    else if (i < 655360) W1b[i - 524288] = f2bf(W1[i - 524288]);
    else if (i < 786432) W2b[i - 655360] = f2bf(W2[i - 655360]);
    else                 Wqb[i - 786432] = f2bf(Wq[i - 786432]);
    if (i < 512)         bkv[i] = (i < 256 ? bk[i] : bv[i - 256]);
    else if (i < 2048)   { int j = i - 512; bg[j] = (j < 768 ? b_ih[j] : b_hh[j - 768]); }
}

// ---------------------------------------------------------------------------
// K/V GEMM: C[131072,512] = X@Wkv^T, split into K,V bf16. 128x128 tiles.
// 1-D grid, j-fastest so the 4 j-blocks of one m-tile are dispatch-adjacent
// (X tile stays L3/L2-hot).
// ---------------------------------------------------------------------------
__global__ __launch_bounds__(256) void gemm_kv(const unsigned short* __restrict__ X,
                                               const unsigned short* __restrict__ W,
                                               const float* __restrict__ bkv,
                                               unsigned short* __restrict__ Ko,
                                               unsigned short* __restrict__ Vo) {
    __shared__ __align__(16) unsigned short As[128 * 64];
    __shared__ __align__(16) unsigned short Bs[128 * 64];
    int t = threadIdx.x, wave = t >> 6, lane = t & 63;
    int wr = wave >> 1, wc = wave & 1;
    int bid = blockIdx.x;
    int m0 = (bid >> 2) * 128;
    int j0 = (bid & 3) * 128;

    f32x4 acc[4][4];
#pragma unroll
    for (int i = 0; i < 4; ++i)
#pragma unroll
        for (int j = 0; j < 4; ++j)
#pragma unroll
            for (int r = 0; r < 4; ++r) acc[i][j][r] = 0.f;

    int row8 = lane >> 3, c8 = (lane & 7) * 8;
    for (int kb = 0; kb < 4; ++kb) {
        int k0 = kb * 64;
#pragma unroll
        for (int i = 0; i < 4; ++i) {
            int rbase = wave * 32 + i * 8;
            gld_lds16(X + (size_t)(m0 + rbase + row8) * 256 + k0 + c8, &As[rbase * 64]);
            gld_lds16(W + (size_t)(j0 + rbase + row8) * 256 + k0 + c8, &Bs[rbase * 64]);
        }
        __syncthreads();
#pragma unroll
        for (int kk = 0; kk < 64; kk += 32) {
            int koff = kk + (lane >> 4) * 8;
            bf16x8 af[4], bf[4];
#pragma unroll
            for (int ti = 0; ti < 4; ++ti)
                af[ti] = *(const bf16x8*)&As[(wr * 64 + ti * 16 + (lane & 15)) * 64 + koff];
#pragma unroll
            for (int tj = 0; tj < 4; ++tj)
                bf[tj] = *(const bf16x8*)&Bs[(wc * 64 + tj * 16 + (lane & 15)) * 64 + koff];
#pragma unroll
            for (int ti = 0; ti < 4; ++ti)
#pragma unroll
                for (int tj = 0; tj < 4; ++tj)
                    acc[ti][tj] = __builtin_amdgcn_mfma_f32_16x16x32_bf16(
                        af[ti], bf[tj], acc[ti][tj], 0, 0, 0);
        }
        __syncthreads();
    }
    bool isK = (j0 < 256);
    unsigned short* base = isK ? Ko : Vo;
    int csub = isK ? 0 : 256;
#pragma unroll
    for (int ti = 0; ti < 4; ++ti)
#pragma unroll
        for (int tj = 0; tj < 4; ++tj) {
            int col = j0 + wc * 64 + tj * 16 + (lane & 15);
            float bias = bkv[col];
            int outc = col - csub;
#pragma unroll
            for (int r = 0; r < 4; ++r) {
                int row = m0 + wr * 64 + ti * 16 + (lane >> 4) * 4 + r;
                base[(size_t)row * 256 + outc] = f2bf(acc[ti][tj][r] + bias);
            }
        }
}

// ---------------------------------------------------------------------------
// Generic MFMA GEMM, slab-staged A and B (both bf16 [rows, K] row-major).
// A selected per-block: j0 < nsplit ? Au : Ah (for the gates GEMM).
// Epilogue: +bias, optional relu, optional fp32 resid, fp32 and/or bf16 out.
// ---------------------------------------------------------------------------
__global__ __launch_bounds__(256) void mfma_gemm_s(
    const unsigned short* __restrict__ Au, const unsigned short* __restrict__ Ah,
    int nsplit, const unsigned short* __restrict__ Bw,
    const float* __restrict__ bias, const float* __restrict__ resid,
    float* __restrict__ outf, unsigned short* __restrict__ outb,
    int N, int K, int relu) {
    __shared__ __align__(16) unsigned short As[128 * 64];
    __shared__ __align__(16) unsigned short Bs[128 * 64];
    int t = threadIdx.x, wave = t >> 6, lane = t & 63;
    int wr = wave >> 1, wc = wave & 1;
    int m0 = blockIdx.x * 128, j0 = blockIdx.y * 128;
    const unsigned short* A = (j0 < nsplit) ? Au : Ah;

    f32x4 acc[4][4];
#pragma unroll
    for (int i = 0; i < 4; ++i)
#pragma unroll
        for (int j = 0; j < 4; ++j)
#pragma unroll
            for (int r = 0; r < 4; ++r) acc[i][j][r] = 0.f;

    int row8 = lane >> 3, c8 = (lane & 7) * 8;
    int nkb = K >> 6;
    for (int kb = 0; kb < nkb; ++kb) {
        int k0 = kb * 64;
#pragma unroll
        for (int i = 0; i < 4; ++i) {
            int rbase = wave * 32 + i * 8;
            gld_lds16(A  + (size_t)(m0 + rbase + row8) * K + k0 + c8, &As[rbase * 64]);
            gld_lds16(Bw + (size_t)(j0 + rbase + row8) * K + k0 + c8, &Bs[rbase * 64]);
        }
        __syncthreads();
#pragma unroll
        for (int kk = 0; kk < 64; kk += 32) {
            int koff = kk + (lane >> 4) * 8;
            bf16x8 af[4], bf[4];
#pragma unroll
            for (int ti = 0; ti < 4; ++ti)
                af[ti] = *(const bf16x8*)&As[(wr * 64 + ti * 16 + (lane & 15)) * 64 + koff];
#pragma unroll
            for (int tj = 0; tj < 4; ++tj)
                bf[tj] = *(const bf16x8*)&Bs[(wc * 64 + tj * 16 + (lane & 15)) * 64 + koff];
#pragma unroll
            for (int ti = 0; ti < 4; ++ti)
#pragma unroll
                for (int tj = 0; tj < 4; ++tj)
                    acc[ti][tj] = __builtin_amdgcn_mfma_f32_16x16x32_bf16(
                        af[ti], bf[tj], acc[ti][tj], 0, 0, 0);
        }
        __syncthreads();
    }
#pragma unroll
    for (int ti = 0; ti < 4; ++ti)
#pragma unroll
        for (int tj = 0; tj < 4; ++tj) {
            int col = j0 + wc * 64 + tj * 16 + (lane & 15);
            float bs = bias[col];
#pragma unroll
            for (int r = 0; r < 4; ++r) {
                int row = m0 + wr * 64 + ti * 16 + (lane >> 4) * 4 + r;
                float v = acc[ti][tj][r] + bs;
                if (relu) v = fmaxf(v, 0.f);
                size_t oi = (size_t)row * N + col;
                if (resid) v += resid[oi];
                if (outf) outf[oi] = v;
                if (outb) outb[oi] = f2bf(v);
            }
        }
}

// ---------------------------------------------------------------------------
// MFMA GEMM with row-LayerNorm fused into A staging (K=256, N=256 fixed).
// Used for q = LN_slot(slots) @ Wq^T + bq -> bf16.
// ---------------------------------------------------------------------------
__global__ __launch_bounds__(256) void mfma_gemm_ln(
    const float* __restrict__ src, const float* __restrict__ lng,
    const float* __restrict__ lnb, const unsigned short* __restrict__ Bw,
    const float* __restrict__ bias, unsigned short* __restrict__ outb) {
    constexpr int ALD = 264;  // pad: bank stride 4, 16B-aligned rows
    __shared__ __align__(16) unsigned short As[128 * ALD];
    __shared__ __align__(16) unsigned short Bs[128 * 64];
    int t = threadIdx.x, wave = t >> 6, lane = t & 63;
    int wr = wave >> 1, wc = wave & 1;
    int m0 = blockIdx.x * 128, j0 = blockIdx.y * 128;

    float4 g4 = *(const float4*)(lng + lane * 4);
    float4 b4 = *(const float4*)(lnb + lane * 4);
    for (int r = 0; r < 32; ++r) {
        int row = wave * 32 + r;
        float4 x = *(const float4*)(src + (size_t)(m0 + row) * 256 + lane * 4);
        float s  = x.x + x.y + x.z + x.w;
        float sq = x.x * x.x + x.y * x.y + x.z * x.z + x.w * x.w;
#pragma unroll
        for (int off = 32; off > 0; off >>= 1) {
            s  += __shfl_xor(s,  off, 64);
            sq += __shfl_xor(sq, off, 64);
        }
        float mean = s * (1.0f / 256.0f);
        float rstd = rsqrtf(sq * (1.0f / 256.0f) - mean * mean + 1e-3f);
        uint2 o;
        o.x = (uint32_t)f2bf((x.x - mean) * rstd * g4.x + b4.x) |
              ((uint32_t)f2bf((x.y - mean) * rstd * g4.y + b4.y) << 16);
        o.y = (uint32_t)f2bf((x.z - mean) * rstd * g4.z + b4.z) |
              ((uint32_t)f2bf((x.w - mean) * rstd * g4.w + b4.w) << 16);
        *(uint2*)&As[row * ALD + lane * 4] = o;
    }
    __syncthreads();

    f32x4 acc[4][4];
#pragma unroll
    for (int i = 0; i < 4; ++i)
#pragma unroll
        for (int j = 0; j < 4; ++j)
#pragma unroll
            for (int r = 0; r < 4; ++r) acc[i][j][r] = 0.f;

    int row8 = lane >> 3, c8 = (lane & 7) * 8;
    for (int kb = 0; kb < 4; ++kb) {
        int k0 = kb * 64;
#pragma unroll
        for (int i = 0; i < 4; ++i) {
            int rbase = wave * 32 + i * 8;
            gld_lds16(Bw + (size_t)(j0 + rbase + row8) * 256 + k0 + c8, &Bs[rbase * 64]);
        }
        __syncthreads();
#pragma unroll
        for (int kk = 0; kk < 64; kk += 32) {
            int koff = kk + (lane >> 4) * 8;
            bf16x8 af[4], bf[4];
#pragma unroll
            for (int ti = 0; ti < 4; ++ti)
                af[ti] = *(const bf16x8*)&As[(wr * 64 + ti * 16 + (lane & 15)) * ALD + k0 + koff];
#pragma unroll
            for (int tj = 0; tj < 4; ++tj)
                bf[tj] = *(const bf16x8*)&Bs[(wc * 64 + tj * 16 + (lane & 15)) * 64 + koff];
#pragma unroll
            for (int ti = 0; ti < 4; ++ti)
#pragma unroll
                for (int tj = 0; tj < 4; ++tj)
                    acc[ti][tj] = __builtin_amdgcn_mfma_f32_16x16x32_bf16(
                        af[ti], bf[tj], acc[ti][tj], 0, 0, 0);
        }
        __syncthreads();
    }
#pragma unroll
    for (int ti = 0; ti < 4; ++ti)
#pragma unroll
        for (int tj = 0; tj < 4; ++tj) {
            int col = j0 + wc * 64 + tj * 16 + (lane & 15);
            float bs = bias[col];
#pragma unroll
            for (int r = 0; r < 4; ++r) {
                int row = m0 + wr * 64 + ti * 16 + (lane >> 4) * 4 + r;
                outb[(size_t)row * 256 + col] = f2bf(acc[ti][tj][r] + bs);
            }
        }
}

// ---------------------------------------------------------------------------
// Fused attention: dots (4s x 4n register tiles) + softmax-over-slots +
// update partials. Block = (batch, 512-n chunk); 256 blocks; no atomics on
// global (deterministic partial buffers).
// ---------------------------------------------------------------------------
__global__ __launch_bounds__(256) void attn_fused(
    const unsigned short* __restrict__ qb,   // [256 rows][256] bf16
    const unsigned short* __restrict__ K,
    const unsigned short* __restrict__ V,
    float* __restrict__ upd_p,               // [8][256][256]
    float* __restrict__ sums_p) {            // [8][256]
    __shared__ __align__(16) unsigned short qs[8 * 256];
    __shared__ __align__(16) float atf[8 * 512];
    __shared__ __align__(16) float pr[4][8 * 256];
    __shared__ float ssum[8];
    int b = blockIdx.x, ch = blockIdx.y, t = threadIdx.x;
    int wave = t >> 6, lane = t & 63;

    *(uint4*)&qs[t * 8] = ((const uint4*)(qb + b * 2048))[t];
    if (t < 8) ssum[t] = 0.f;
    __syncthreads();

    // ---- dots: thread tile 4 slots x 4 n ----
    int sg = t >> 7;        // 0..1 (slots 0-3 / 4-7)
    int ng = t & 127;       // 0..127
    int nbase = ch * 512 + ng * 4;
    const unsigned short* kr = K + ((size_t)b * 4096 + nbase) * 256;
    float acc[4][4];
#pragma unroll
    for (int i = 0; i < 4; ++i)
#pragma unroll
        for (int j = 0; j < 4; ++j) acc[i][j] = 0.f;
    for (int c = 0; c < 32; ++c) {
        float qf[4][8];
#pragma unroll
        for (int si = 0; si < 4; ++si)
            unpack8(*(const uint4*)&qs[(sg * 4 + si) * 256 + c * 8], qf[si]);
#pragma unroll
        for (int r = 0; r < 4; ++r) {
            float kf[8];
            unpack8(*(const uint4*)(kr + (size_t)r * 256 + c * 8), kf);
#pragma unroll
            for (int si = 0; si < 4; ++si) {
                float d = qf[si][0] * kf[0] + qf[si][1] * kf[1] +
                          qf[si][2] * kf[2] + qf[si][3] * kf[3] +
                          qf[si][4] * kf[4] + qf[si][5] * kf[5] +
                          qf[si][6] * kf[6] + qf[si][7] * kf[7];
                acc[si][r] += d;
            }
        }
    }
#pragma unroll
    for (int si = 0; si < 4; ++si) {
        float4 o = make_float4(acc[si][0] * 0.0625f, acc[si][1] * 0.0625f,
                               acc[si][2] * 0.0625f, acc[si][3] * 0.0625f);
        *(float4*)&atf[(sg * 4 + si) * 512 + ng * 4] = o;
    }
    __syncthreads();

    // ---- softmax over slots, 2 n per thread ----
    float ts[8];
#pragma unroll
    for (int s = 0; s < 8; ++s) ts[s] = 0.f;
#pragma unroll
    for (int rep = 0; rep < 2; ++rep) {
        int nl = t * 2 + rep;
        float v[8];
#pragma unroll
        for (int s = 0; s < 8; ++s) v[s] = atf[s * 512 + nl];
        float m = v[0];
#pragma unroll
        for (int s = 1; s < 8; ++s) m = fmaxf(m, v[s]);
        float sum = 0.f;
#pragma unroll
        for (int s = 0; s < 8; ++s) { v[s] = __expf(v[s] - m); sum += v[s]; }
        float inv = 1.0f / sum;
#pragma unroll
        for (int s = 0; s < 8; ++s) {
            float a = v[s] * inv + 1e-8f;
            atf[s * 512 + nl] = a;
            ts[s] += a;
        }
    }
#pragma unroll
    for (int s = 0; s < 8; ++s) {
#pragma unroll
        for (int off = 32; off > 0; off >>= 1) ts[s] += __shfl_xor(ts[s], off, 64);
    }
    if (lane == 0) {
#pragma unroll
        for (int s = 0; s < 8; ++s) atomicAdd(&ssum[s], ts[s]);
    }
    __syncthreads();
    if (t < 8) sums_p[ch * 256 + b * 8 + t] = ssum[t];

    // ---- update: wave w covers 128 n, lane owns d-quad ----
    float ua[8][4];
#pragma unroll
    for (int s = 0; s < 8; ++s)
#pragma unroll
        for (int k = 0; k < 4; ++k) ua[s][k] = 0.f;
    const unsigned short* vb = V + ((size_t)b * 4096 + ch * 512) * 256 + lane * 4;
    for (int g = 0; g < 32; ++g) {
        int nl = wave * 128 + g * 4;
        float4 a4[8];
#pragma unroll
        for (int s = 0; s < 8; ++s) a4[s] = *(const float4*)&atf[s * 512 + nl];
        const unsigned short* vrow = vb + (size_t)nl * 256;
#define UPD_STEP(kk, comp)                                                     \
        {                                                                      \
            uint2 vv = *(const uint2*)(vrow + (size_t)kk * 256);               \
            float v0 = bf2f_lo(vv.x), v1 = bf2f_hi(vv.x);                      \
            float v2 = bf2f_lo(vv.y), v3 = bf2f_hi(vv.y);                      \
            _Pragma("unroll")                                                  \
            for (int s = 0; s < 8; ++s) {                                      \
                float a = a4[s].comp;                                          \
                ua[s][0] += a * v0; ua[s][1] += a * v1;                        \
                ua[s][2] += a * v2; ua[s][3] += a * v3;                        \
            }                                                                  \
        }
        UPD_STEP(0, x) UPD_STEP(1, y) UPD_STEP(2, z) UPD_STEP(3, w)
#undef UPD_STEP
    }
#pragma unroll
    for (int s = 0; s < 8; ++s)
        *(float4*)&pr[wave][s * 256 + lane * 4] = *(float4*)ua[s];
    __syncthreads();
    for (int i = t; i < 2048; i += 256) {
        float vsum = pr[0][i] + pr[1][i] + pr[2][i] + pr[3][i];
        upd_p[(size_t)ch * 65536 + (size_t)b * 2048 + i] = vsum;
    }
}

// ---------------------------------------------------------------------------
// Reduce update partials -> u bf16 (normalized); convert slots -> h bf16.
// ---------------------------------------------------------------------------
__global__ __launch_bounds__(256) void u_k(const float* __restrict__ upd_p,
                                           const float* __restrict__ sums_p,
                                           const float* __restrict__ cur,
                                           unsigned short* __restrict__ ub,
                                           unsigned short* __restrict__ hb) {
    int i = blockIdx.x * 256 + threadIdx.x;   // 0..65535
    int row = i >> 8;
    float ssv = 0.f, uv = 0.f;
#pragma unroll
    for (int c = 0; c < 8; ++c) {
        ssv += sums_p[c * 256 + row];
        uv  += upd_p[(size_t)c * 65536 + i];
    }
    ub[i] = f2bf(uv / ssv);
    hb[i] = f2bf(cur[i]);
}

// ---------------------------------------------------------------------------
// GRU combine + LayerNorm(mlp) -> s1 fp32, lnm bf16. Block = batch.
// ---------------------------------------------------------------------------
__global__ __launch_bounds__(256) void gru_ln_k(const float* __restrict__ gates,
                                                const float* __restrict__ cur,
                                                const float* __restrict__ g_mlp,
                                                const float* __restrict__ b_mlp,
                                                float* __restrict__ s1,
                                                unsigned short* __restrict__ lnm) {
    __shared__ float hn[8 * 256];
    int b = blockIdx.x, t = threadIdx.x;
#pragma unroll
    for (int p = 0; p < 8; ++p) {
        int idx = p * 256 + t;
        int s = idx >> 8, j = idx & 255;
        const float* gr = gates + ((size_t)b * 8 + s) * 1536;
        float r  = sigf(gr[j] + gr[768 + j]);
        float z  = sigf(gr[256 + j] + gr[1024 + j]);
        float nn = tanhf(gr[512 + j] + r * gr[1280 + j]);
        float h  = cur[((size_t)b * 8 + s) * 256 + j];
        float hp = (1.0f - z) * nn + z * h;
        hn[idx] = hp;
        s1[((size_t)b * 8 + s) * 256 + j] = hp;
    }
    __syncthreads();
    int wave = t >> 6, lane = t & 63;
    float4 g4 = *(const float4*)(g_mlp + lane * 4);
    float4 b4 = *(const float4*)(b_mlp + lane * 4);
#pragma unroll
    for (int rep = 0; rep < 2; ++rep) {
        int s = wave * 2 + rep;
        float4 x = *(const float4*)&hn[s * 256 + lane * 4];
        float sm  = x.x + x.y + x.z + x.w;
        float sq = x.x * x.x + x.y * x.y + x.z * x.z + x.w * x.w;
#pragma unroll
        for (int off = 32; off > 0; off >>= 1) {
            sm += __shfl_xor(sm, off, 64);
            sq += __shfl_xor(sq, off, 64);
        }
        float mean = sm * (1.0f / 256.0f);
        float rstd = rsqrtf(sq * (1.0f / 256.0f) - mean * mean + 1e-3f);
        uint2 o;
        o.x = (uint32_t)f2bf((x.x - mean) * rstd * g4.x + b4.x) |
              ((uint32_t)f2bf((x.y - mean) * rstd * g4.y + b4.y) << 16);
        o.y = (uint32_t)f2bf((x.z - mean) * rstd * g4.z + b4.z) |
              ((uint32_t)f2bf((x.w - mean) * rstd * g4.w + b4.w) << 16);
        *(uint2*)(lnm + ((size_t)b * 8 + s) * 256 + lane * 4) = o;
    }
}

// ---------------------------------------------------------------------------
extern "C" void kernel_launch(void* const* d_in, const int* in_sizes, int n_in,
                              void* d_out, int out_size, void* d_ws, size_t ws_size,
                              hipStream_t stream) {
    const float* inputs    = (const float*)d_in[0];
    const float* slots_in  = (const float*)d_in[1];
    const float* ln_in_g   = (const float*)d_in[3];
    const float* ln_in_b   = (const float*)d_in[4];
    const float* ln_slot_g = (const float*)d_in[5];
    const float* ln_slot_b = (const float*)d_in[6];
    const float* ln_mlp_g  = (const float*)d_in[7];
    const float* ln_mlp_b  = (const float*)d_in[8];
    const float* Wq   = (const float*)d_in[9];
    const float* bq   = (const float*)d_in[10];
    const float* Wk   = (const float*)d_in[11];
    const float* bk   = (const float*)d_in[12];
    const float* Wv   = (const float*)d_in[13];
    const float* bv   = (const float*)d_in[14];
    const float* W_ih = (const float*)d_in[15];
    const float* b_ih = (const float*)d_in[16];
    const float* W_hh = (const float*)d_in[17];
    const float* b_hh = (const float*)d_in[18];
    const float* W1   = (const float*)d_in[19];
    const float* b1   = (const float*)d_in[20];
    const float* W2   = (const float*)d_in[21];
    const float* b2   = (const float*)d_in[22];

    char* p = (char*)d_ws;
    size_t off = 0;
    auto take = [&](size_t bytes) -> char* {
        char* r = p + off;
        off += (bytes + 255) & ~(size_t)255;
        return r;
    };
    unsigned short* xbf  = (unsigned short*)take((size_t)131072 * 256 * 2);
    unsigned short* Kb   = (unsigned short*)take((size_t)131072 * 256 * 2);
    unsigned short* Vb   = (unsigned short*)take((size_t)131072 * 256 * 2);
    unsigned short* Wkv  = (unsigned short*)take(131072 * 2);
    unsigned short* Wg   = (unsigned short*)take(393216 * 2);
    unsigned short* W1b  = (unsigned short*)take(131072 * 2);
    unsigned short* W2b  = (unsigned short*)take(131072 * 2);
    unsigned short* Wqb  = (unsigned short*)take(65536 * 2);
    float* bkv   = (float*)take(512 * 4);
    float* bg    = (float*)take(1536 * 4);
    unsigned short* qbuf = (unsigned short*)take(65536 * 2);
    float* upd_p = (float*)take((size_t)8 * 65536 * 4);
    float* sums_p= (float*)take(8 * 256 * 4);
    unsigned short* ub = (unsigned short*)take(65536 * 2);
    unsigned short* hb = (unsigned short*)take(65536 * 2);
    float* gates = (float*)take((size_t)256 * 1536 * 4);
    float* s1    = (float*)take(65536 * 4);
    unsigned short* lnm    = (unsigned short*)take(65536 * 2);
    unsigned short* hidden = (unsigned short*)take((size_t)256 * 512 * 2);
    float* sA    = (float*)take(65536 * 4);
    float* sB    = (float*)take(65536 * 4);

    ln_in_k<<<32768, 256, 0, stream>>>(inputs, ln_in_g, ln_in_b, xbf);
    cvt_all<<<3328, 256, 0, stream>>>(Wk, Wv, W_ih, W_hh, W1, W2, Wq,
                                      bk, bv, b_ih, b_hh,
                                      Wkv, Wg, W1b, W2b, Wqb, bkv, bg);
    gemm_kv<<<4096, 256, 0, stream>>>(xbf, Wkv, bkv, Kb, Vb);
    mfma_gemm_ln<<<dim3(2, 2), 256, 0, stream>>>(slots_in, ln_slot_g, ln_slot_b,
                                                 Wqb, bq, qbuf);

    const float* cur = slots_in;
    float* nxt[3] = {sA, sB, (float*)d_out};
    for (int it = 0; it < 3; ++it) {
        attn_fused<<<dim3(32, 8), 256, 0, stream>>>(qbuf, Kb, Vb, upd_p, sums_p);
        u_k<<<256, 256, 0, stream>>>(upd_p, sums_p, cur, ub, hb);
        mfma_gemm_s<<<dim3(2, 12), 256, 0, stream>>>(ub, hb, 768, Wg, bg, nullptr,
                                                     gates, nullptr, 1536, 256, 0);
        gru_ln_k<<<32, 256, 0, stream>>>(gates, cur, ln_mlp_g, ln_mlp_b, s1, lnm);
        mfma_gemm_s<<<dim3(2, 4), 256, 0, stream>>>(lnm, lnm, 1 << 30, W1b, b1, nullptr,
                                                    nullptr, hidden, 512, 256, 1);
        mfma_gemm_s<<<dim3(2, 2), 256, 0, stream>>>(hidden, hidden, 1 << 30, W2b, b2, s1,
                                                    nxt[it], nullptr, 256, 512, 0);
        if (it < 2)
            mfma_gemm_ln<<<dim3(2, 2), 256, 0, stream>>>(nxt[it], ln_slot_g, ln_slot_b,
                                                         Wqb, bq, qbuf);
        cur = nxt[it];
    }
    (void)in_sizes; (void)n_in; (void)out_size; (void)ws_size;
}

// Round 3
// 654.525 us; speedup vs baseline: 1.2903x; 1.0435x over previous
//
#include <hip/hip_runtime.h>
#include <stdint.h>

// B=32, N=4096, D=256, S=8, H_MLP=512, 3 iterations.

typedef __attribute__((ext_vector_type(8))) short bf16x8;
typedef __attribute__((ext_vector_type(4))) float f32x4;

__device__ __forceinline__ float bf2f_lo(uint32_t u) {
    union { uint32_t u; float f; } v; v.u = u << 16; return v.f;
}
__device__ __forceinline__ float bf2f_hi(uint32_t u) {
    union { uint32_t u; float f; } v; v.u = u & 0xffff0000u; return v.f;
}
__device__ __forceinline__ unsigned short f2bf(float f) {
    union { float f; uint32_t u; } v; v.f = f;
    return (unsigned short)((v.u + 0x7fffu + ((v.u >> 16) & 1u)) >> 16);
}
__device__ __forceinline__ void gld_lds16(const void* g, void* l) {
    __builtin_amdgcn_global_load_lds(
        (__attribute__((address_space(1))) unsigned int*)g,
        (__attribute__((address_space(3))) unsigned int*)l, 16, 0, 0);
}
__device__ __forceinline__ void unpack8(uint4 v, float* f) {
    f[0] = bf2f_lo(v.x); f[1] = bf2f_hi(v.x); f[2] = bf2f_lo(v.y); f[3] = bf2f_hi(v.y);
    f[4] = bf2f_lo(v.z); f[5] = bf2f_hi(v.z); f[6] = bf2f_lo(v.w); f[7] = bf2f_hi(v.w);
}
__device__ __forceinline__ float sigf(float x) { return 1.0f / (1.0f + __expf(-x)); }

// ---------------------------------------------------------------------------
// Convert all weights to bf16, pack biases.
// ---------------------------------------------------------------------------
__global__ __launch_bounds__(256) void cvt_all(
    const float* __restrict__ Wk, const float* __restrict__ Wv,
    const float* __restrict__ W_ih, const float* __restrict__ W_hh,
    const float* __restrict__ W1, const float* __restrict__ W2,
    const float* __restrict__ Wq,
    const float* __restrict__ bk, const float* __restrict__ bv,
    const float* __restrict__ b_ih, const float* __restrict__ b_hh,
    unsigned short* __restrict__ Wkv, unsigned short* __restrict__ Wg,
    unsigned short* __restrict__ W1b, unsigned short* __restrict__ W2b,
    unsigned short* __restrict__ Wqb,
    float* __restrict__ bkv, float* __restrict__ bg) {
    int i = blockIdx.x * 256 + threadIdx.x;
    if (i < 131072)      Wkv[i] = f2bf(i < 65536 ? Wk[i] : Wv[i - 65536]);
    else if (i < 524288) { int j = i - 131072; Wg[j] = f2bf(j < 196608 ? W_ih[j] : W_hh[j - 196608]); }
    else if (i < 655360) W1b[i - 524288] = f2bf(W1[i - 524288]);
    else if (i < 786432) W2b[i - 655360] = f2bf(W2[i - 655360]);
    else                 Wqb[i - 786432] = f2bf(Wq[i - 786432]);
    if (i < 512)         bkv[i] = (i < 256 ? bk[i] : bv[i - 256]);
    else if (i < 2048)   { int j = i - 512; bg[j] = (j < 768 ? b_ih[j] : b_hh[j - 768]); }
}

// ---------------------------------------------------------------------------
// Fused LN(inputs) + K/V GEMM.  Block = 128-row tile, ALL 512 output cols.
// 512 threads (8 waves, 2x4 wave grid of 64x128 tiles).  A (LN'd, bf16) is
// built in LDS once; only the B (weight) slab restages per K-step.
// ---------------------------------------------------------------------------
__global__ __launch_bounds__(512, 1) void lngemm_kv(
    const float* __restrict__ in, const float* __restrict__ gg,
    const float* __restrict__ bb, const unsigned short* __restrict__ W,
    const float* __restrict__ bkv,
    unsigned short* __restrict__ Ko, unsigned short* __restrict__ Vo) {
    __shared__ __align__(16) unsigned short As[4 * 128 * 64];  // [kb][row][64]
    __shared__ __align__(16) unsigned short Bs[512 * 64];
    int t = threadIdx.x, wave = t >> 6, lane = t & 63;
    int m0 = blockIdx.x * 128;

    // ---- LN phase: 4 threads per row, 64 cols each, two-pass ----
    {
        int row = t >> 2, q4 = t & 3;
        const float* rp = in + (size_t)(m0 + row) * 256 + q4 * 64;
        float s = 0.f, sq = 0.f;
#pragma unroll
        for (int i = 0; i < 16; ++i) {
            float4 x = *(const float4*)(rp + i * 4);
            s  += x.x + x.y + x.z + x.w;
            sq += x.x * x.x + x.y * x.y + x.z * x.z + x.w * x.w;
        }
        s  += __shfl_xor(s, 1, 64);  sq += __shfl_xor(sq, 1, 64);
        s  += __shfl_xor(s, 2, 64);  sq += __shfl_xor(sq, 2, 64);
        float mean = s * (1.0f / 256.0f);
        float rstd = rsqrtf(sq * (1.0f / 256.0f) - mean * mean + 1e-3f);
        const float* gp = gg + q4 * 64;
        const float* bp = bb + q4 * 64;
        unsigned short* dst = &As[(q4 * 128 + row) * 64];
#pragma unroll
        for (int i = 0; i < 16; ++i) {
            float4 x = *(const float4*)(rp + i * 4);
            float4 g4 = *(const float4*)(gp + i * 4);
            float4 b4 = *(const float4*)(bp + i * 4);
            uint2 o;
            o.x = (uint32_t)f2bf((x.x - mean) * rstd * g4.x + b4.x) |
                  ((uint32_t)f2bf((x.y - mean) * rstd * g4.y + b4.y) << 16);
            o.y = (uint32_t)f2bf((x.z - mean) * rstd * g4.z + b4.z) |
                  ((uint32_t)f2bf((x.w - mean) * rstd * g4.w + b4.w) << 16);
            *(uint2*)(dst + i * 4) = o;
        }
    }
    __syncthreads();

    int wr = wave >> 2, wc = wave & 3;  // 2 x 4 wave grid
    f32x4 acc[4][8];
#pragma unroll
    for (int i = 0; i < 4; ++i)
#pragma unroll
        for (int j = 0; j < 8; ++j)
#pragma unroll
            for (int r = 0; r < 4; ++r) acc[i][j][r] = 0.f;

    for (int kb = 0; kb < 4; ++kb) {
        // stage Bs: 512 weight rows x 64 k
#pragma unroll
        for (int i = 0; i < 8; ++i) {
            int rbase = wave * 64 + i * 8;
            gld_lds16(W + (size_t)(rbase + (lane >> 3)) * 256 + kb * 64 + (lane & 7) * 8,
                      &Bs[rbase * 64]);
        }
        __syncthreads();
#pragma unroll
        for (int kk = 0; kk < 64; kk += 32) {
            int koff = kk + (lane >> 4) * 8;
            bf16x8 af[4], bf[8];
#pragma unroll
            for (int ti = 0; ti < 4; ++ti)
                af[ti] = *(const bf16x8*)&As[((kb * 128) + wr * 64 + ti * 16 + (lane & 15)) * 64 + koff];
#pragma unroll
            for (int tj = 0; tj < 8; ++tj)
                bf[tj] = *(const bf16x8*)&Bs[(wc * 128 + tj * 16 + (lane & 15)) * 64 + koff];
#pragma unroll
            for (int ti = 0; ti < 4; ++ti)
#pragma unroll
                for (int tj = 0; tj < 8; ++tj)
                    acc[ti][tj] = __builtin_amdgcn_mfma_f32_16x16x32_bf16(
                        af[ti], bf[tj], acc[ti][tj], 0, 0, 0);
        }
        __syncthreads();
    }
#pragma unroll
    for (int ti = 0; ti < 4; ++ti)
#pragma unroll
        for (int tj = 0; tj < 8; ++tj) {
            int col = wc * 128 + tj * 16 + (lane & 15);
            float bias = bkv[col];
            unsigned short* base = (col < 256) ? Ko : Vo;
            int outc = (col < 256) ? col : col - 256;
#pragma unroll
            for (int r = 0; r < 4; ++r) {
                int row = m0 + wr * 64 + ti * 16 + (lane >> 4) * 4 + r;
                base[(size_t)row * 256 + outc] = f2bf(acc[ti][tj][r] + bias);
            }
        }
}

// ---------------------------------------------------------------------------
// MFMA GEMM with row-LayerNorm fused into A staging; q0 = LN(slots)@Wq^T+bq.
// ---------------------------------------------------------------------------
__global__ __launch_bounds__(256) void mfma_gemm_ln(
    const float* __restrict__ src, const float* __restrict__ lng,
    const float* __restrict__ lnb, const unsigned short* __restrict__ Bw,
    const float* __restrict__ bias, unsigned short* __restrict__ outb) {
    constexpr int ALD = 264;
    __shared__ __align__(16) unsigned short As[128 * ALD];
    __shared__ __align__(16) unsigned short Bs[128 * 64];
    int t = threadIdx.x, wave = t >> 6, lane = t & 63;
    int wr = wave >> 1, wc = wave & 1;
    int m0 = blockIdx.x * 128, j0 = blockIdx.y * 128;

    float4 g4 = *(const float4*)(lng + lane * 4);
    float4 b4 = *(const float4*)(lnb + lane * 4);
    for (int r = 0; r < 32; ++r) {
        int row = wave * 32 + r;
        float4 x = *(const float4*)(src + (size_t)(m0 + row) * 256 + lane * 4);
        float s  = x.x + x.y + x.z + x.w;
        float sq = x.x * x.x + x.y * x.y + x.z * x.z + x.w * x.w;
#pragma unroll
        for (int off = 32; off > 0; off >>= 1) {
            s  += __shfl_xor(s,  off, 64);
            sq += __shfl_xor(sq, off, 64);
        }
        float mean = s * (1.0f / 256.0f);
        float rstd = rsqrtf(sq * (1.0f / 256.0f) - mean * mean + 1e-3f);
        uint2 o;
        o.x = (uint32_t)f2bf((x.x - mean) * rstd * g4.x + b4.x) |
              ((uint32_t)f2bf((x.y - mean) * rstd * g4.y + b4.y) << 16);
        o.y = (uint32_t)f2bf((x.z - mean) * rstd * g4.z + b4.z) |
              ((uint32_t)f2bf((x.w - mean) * rstd * g4.w + b4.w) << 16);
        *(uint2*)&As[row * ALD + lane * 4] = o;
    }
    __syncthreads();

    f32x4 acc[4][4];
#pragma unroll
    for (int i = 0; i < 4; ++i)
#pragma unroll
        for (int j = 0; j < 4; ++j)
#pragma unroll
            for (int r = 0; r < 4; ++r) acc[i][j][r] = 0.f;

    for (int kb = 0; kb < 4; ++kb) {
        int k0 = kb * 64;
#pragma unroll
        for (int i = 0; i < 4; ++i) {
            int rbase = wave * 32 + i * 8;
            gld_lds16(Bw + (size_t)(j0 + rbase + (lane >> 3)) * 256 + k0 + (lane & 7) * 8,
                      &Bs[rbase * 64]);
        }
        __syncthreads();
#pragma unroll
        for (int kk = 0; kk < 64; kk += 32) {
            int koff = kk + (lane >> 4) * 8;
            bf16x8 af[4], bf[4];
#pragma unroll
            for (int ti = 0; ti < 4; ++ti)
                af[ti] = *(const bf16x8*)&As[(wr * 64 + ti * 16 + (lane & 15)) * ALD + k0 + koff];
#pragma unroll
            for (int tj = 0; tj < 4; ++tj)
                bf[tj] = *(const bf16x8*)&Bs[(wc * 64 + tj * 16 + (lane & 15)) * 64 + koff];
#pragma unroll
            for (int ti = 0; ti < 4; ++ti)
#pragma unroll
                for (int tj = 0; tj < 4; ++tj)
                    acc[ti][tj] = __builtin_amdgcn_mfma_f32_16x16x32_bf16(
                        af[ti], bf[tj], acc[ti][tj], 0, 0, 0);
        }
        __syncthreads();
    }
#pragma unroll
    for (int ti = 0; ti < 4; ++ti)
#pragma unroll
        for (int tj = 0; tj < 4; ++tj) {
            int col = j0 + wc * 64 + tj * 16 + (lane & 15);
            float bs = bias[col];
#pragma unroll
            for (int r = 0; r < 4; ++r) {
                int row = m0 + wr * 64 + ti * 16 + (lane >> 4) * 4 + r;
                outb[(size_t)row * 256 + col] = f2bf(acc[ti][tj][r] + bs);
            }
        }
}

// ---------------------------------------------------------------------------
// Fused attention: dots + softmax-over-slots + update, atomically accumulated
// into upd[256][256] / sums[256] (zeroed by a memset before each launch).
// Block = (batch, 512-n chunk).
// ---------------------------------------------------------------------------
__global__ __launch_bounds__(256) void attn_fused(
    const unsigned short* __restrict__ qb, const unsigned short* __restrict__ K,
    const unsigned short* __restrict__ V,
    float* __restrict__ upd, float* __restrict__ sums) {
    __shared__ __align__(16) unsigned short qs[8 * 256];
    __shared__ __align__(16) float atf[8 * 512];
    __shared__ __align__(16) float pr[4][8 * 256];
    __shared__ float ssum[8];
    int b = blockIdx.x, ch = blockIdx.y, t = threadIdx.x;
    int wave = t >> 6, lane = t & 63;

    *(uint4*)&qs[t * 8] = ((const uint4*)(qb + b * 2048))[t];
    if (t < 8) ssum[t] = 0.f;
    __syncthreads();

    int sg = t >> 7, ng = t & 127;
    int nbase = ch * 512 + ng * 4;
    const unsigned short* kr = K + ((size_t)b * 4096 + nbase) * 256;
    float acc[4][4];
#pragma unroll
    for (int i = 0; i < 4; ++i)
#pragma unroll
        for (int j = 0; j < 4; ++j) acc[i][j] = 0.f;
    for (int c = 0; c < 32; ++c) {
        float qf[4][8];
#pragma unroll
        for (int si = 0; si < 4; ++si)
            unpack8(*(const uint4*)&qs[(sg * 4 + si) * 256 + c * 8], qf[si]);
#pragma unroll
        for (int r = 0; r < 4; ++r) {
            float kf[8];
            unpack8(*(const uint4*)(kr + (size_t)r * 256 + c * 8), kf);
#pragma unroll
            for (int si = 0; si < 4; ++si)
                acc[si][r] += qf[si][0] * kf[0] + qf[si][1] * kf[1] +
                              qf[si][2] * kf[2] + qf[si][3] * kf[3] +
                              qf[si][4] * kf[4] + qf[si][5] * kf[5] +
                              qf[si][6] * kf[6] + qf[si][7] * kf[7];
        }
    }
#pragma unroll
    for (int si = 0; si < 4; ++si)
        *(float4*)&atf[(sg * 4 + si) * 512 + ng * 4] =
            make_float4(acc[si][0] * 0.0625f, acc[si][1] * 0.0625f,
                        acc[si][2] * 0.0625f, acc[si][3] * 0.0625f);
    __syncthreads();

    float ts[8];
#pragma unroll
    for (int s = 0; s < 8; ++s) ts[s] = 0.f;
#pragma unroll
    for (int rep = 0; rep < 2; ++rep) {
        int nl = t * 2 + rep;
        float v[8];
#pragma unroll
        for (int s = 0; s < 8; ++s) v[s] = atf[s * 512 + nl];
        float m = v[0];
#pragma unroll
        for (int s = 1; s < 8; ++s) m = fmaxf(m, v[s]);
        float sum = 0.f;
#pragma unroll
        for (int s = 0; s < 8; ++s) { v[s] = __expf(v[s] - m); sum += v[s]; }
        float inv = 1.0f / sum;
#pragma unroll
        for (int s = 0; s < 8; ++s) {
            float a = v[s] * inv + 1e-8f;
            atf[s * 512 + nl] = a;
            ts[s] += a;
        }
    }
#pragma unroll
    for (int s = 0; s < 8; ++s) {
#pragma unroll
        for (int off = 32; off > 0; off >>= 1) ts[s] += __shfl_xor(ts[s], off, 64);
    }
    if (lane == 0) {
#pragma unroll
        for (int s = 0; s < 8; ++s) atomicAdd(&ssum[s], ts[s]);
    }
    __syncthreads();
    if (t < 8) atomicAdd(&sums[b * 8 + t], ssum[t]);

    float ua[8][4];
#pragma unroll
    for (int s = 0; s < 8; ++s)
#pragma unroll
        for (int k = 0; k < 4; ++k) ua[s][k] = 0.f;
    const unsigned short* vb = V + ((size_t)b * 4096 + ch * 512) * 256 + lane * 4;
    for (int g = 0; g < 32; ++g) {
        int nl = wave * 128 + g * 4;
        float4 a4[8];
#pragma unroll
        for (int s = 0; s < 8; ++s) a4[s] = *(const float4*)&atf[s * 512 + nl];
        const unsigned short* vrow = vb + (size_t)nl * 256;
#define UPD_STEP(kk, comp)                                                     \
        {                                                                      \
            uint2 vv = *(const uint2*)(vrow + (size_t)kk * 256);               \
            float v0 = bf2f_lo(vv.x), v1 = bf2f_hi(vv.x);                      \
            float v2 = bf2f_lo(vv.y), v3 = bf2f_hi(vv.y);                      \
            _Pragma("unroll")                                                  \
            for (int s = 0; s < 8; ++s) {                                      \
                float a = a4[s].comp;                                          \
                ua[s][0] += a * v0; ua[s][1] += a * v1;                        \
                ua[s][2] += a * v2; ua[s][3] += a * v3;                        \
            }                                                                  \
        }
        UPD_STEP(0, x) UPD_STEP(1, y) UPD_STEP(2, z) UPD_STEP(3, w)
#undef UPD_STEP
    }
#pragma unroll
    for (int s = 0; s < 8; ++s)
        *(float4*)&pr[wave][s * 256 + lane * 4] = *(float4*)ua[s];
    __syncthreads();
    for (int i = t; i < 2048; i += 256) {
        float vsum = pr[0][i] + pr[1][i] + pr[2][i] + pr[3][i];
        atomicAdd(&upd[(size_t)b * 2048 + i], vsum);
    }
}

// ---------------------------------------------------------------------------
// Gates GEMM [256 x 1536] with fused A-staging: A = u (=upd/sums) for the
// W_ih half (j0<768), A = cur slots for the W_hh half.  Grid (2, 12).
// ---------------------------------------------------------------------------
__global__ __launch_bounds__(256) void slot_gates(
    const float* __restrict__ upd, const float* __restrict__ sums,
    const float* __restrict__ cur, const unsigned short* __restrict__ Wg,
    const float* __restrict__ bg, float* __restrict__ gates) {
    __shared__ __align__(16) unsigned short As[4 * 128 * 64];
    __shared__ __align__(16) unsigned short Bs[128 * 64];
    int t = threadIdx.x, wave = t >> 6, lane = t & 63;
    int wr = wave >> 1, wc = wave & 1;
    int m0 = blockIdx.x * 128, j0 = blockIdx.y * 128;

    if (j0 < 768) {
        for (int idx = t; idx < 32768; idx += 256) {
            int row = idx >> 8, c = idx & 255;
            float u = upd[(size_t)(m0 + row) * 256 + c] / sums[m0 + row];
            As[((c >> 6) * 128 + row) * 64 + (c & 63)] = f2bf(u);
        }
    } else {
        for (int idx = t; idx < 32768; idx += 256) {
            int row = idx >> 8, c = idx & 255;
            As[((c >> 6) * 128 + row) * 64 + (c & 63)] =
                f2bf(cur[(size_t)(m0 + row) * 256 + c]);
        }
    }
    __syncthreads();

    f32x4 acc[4][4];
#pragma unroll
    for (int i = 0; i < 4; ++i)
#pragma unroll
        for (int j = 0; j < 4; ++j)
#pragma unroll
            for (int r = 0; r < 4; ++r) acc[i][j][r] = 0.f;

    for (int kb = 0; kb < 4; ++kb) {
#pragma unroll
        for (int i = 0; i < 4; ++i) {
            int rbase = wave * 32 + i * 8;
            gld_lds16(Wg + (size_t)(j0 + rbase + (lane >> 3)) * 256 + kb * 64 + (lane & 7) * 8,
                      &Bs[rbase * 64]);
        }
        __syncthreads();
#pragma unroll
        for (int kk = 0; kk < 64; kk += 32) {
            int koff = kk + (lane >> 4) * 8;
            bf16x8 af[4], bf[4];
#pragma unroll
            for (int ti = 0; ti < 4; ++ti)
                af[ti] = *(const bf16x8*)&As[((kb * 128) + wr * 64 + ti * 16 + (lane & 15)) * 64 + koff];
#pragma unroll
            for (int tj = 0; tj < 4; ++tj)
                bf[tj] = *(const bf16x8*)&Bs[(wc * 64 + tj * 16 + (lane & 15)) * 64 + koff];
#pragma unroll
            for (int ti = 0; ti < 4; ++ti)
#pragma unroll
                for (int tj = 0; tj < 4; ++tj)
                    acc[ti][tj] = __builtin_amdgcn_mfma_f32_16x16x32_bf16(
                        af[ti], bf[tj], acc[ti][tj], 0, 0, 0);
        }
        __syncthreads();
    }
#pragma unroll
    for (int ti = 0; ti < 4; ++ti)
#pragma unroll
        for (int tj = 0; tj < 4; ++tj) {
            int col = j0 + wc * 64 + tj * 16 + (lane & 15);
            float bs = bg[col];
#pragma unroll
            for (int r = 0; r < 4; ++r) {
                int row = m0 + wr * 64 + ti * 16 + (lane >> 4) * 4 + r;
                gates[(size_t)row * 1536 + col] = acc[ti][tj][r] + bs;
            }
        }
}

// ---------------------------------------------------------------------------
// Slot tail: GRU combine + LN + MLP1(relu) + MLP2(+resid) -> new slots,
// then (unless last) slot-LN + q GEMM.  One block per batch (32 blocks).
// B-fragments loaded straight from global (weights L2/L3-hot).
// ---------------------------------------------------------------------------
__global__ __launch_bounds__(256) void slot_tail(
    const float* __restrict__ gates, const float* __restrict__ cur,
    const float* __restrict__ g_mlp, const float* __restrict__ b_mlp,
    const unsigned short* __restrict__ W1b, const float* __restrict__ b1,
    const unsigned short* __restrict__ W2b, const float* __restrict__ b2,
    const float* __restrict__ g_slot, const float* __restrict__ b_slot,
    const unsigned short* __restrict__ Wqb, const float* __restrict__ bq,
    float* __restrict__ slots_out, unsigned short* __restrict__ qbuf,
    int do_q) {
    __shared__ float hn[2048];                         // GRU output (8x256)
    __shared__ float sn[2048];                         // new slots (8x256)
    __shared__ __align__(16) unsigned short A1[16 * 264];
    __shared__ __align__(16) unsigned short A2[16 * 520];
    int b = blockIdx.x, t = threadIdx.x;
    int wave = t >> 6, lane = t & 63;

    // ---- GRU combine ----
#pragma unroll
    for (int p = 0; p < 8; ++p) {
        int idx = p * 256 + t;
        int s = idx >> 8, j = idx & 255;
        const float* gr = gates + ((size_t)b * 8 + s) * 1536;
        float r  = sigf(gr[j] + gr[768 + j]);
        float z  = sigf(gr[256 + j] + gr[1024 + j]);
        float nn = tanhf(gr[512 + j] + r * gr[1280 + j]);
        float h  = cur[((size_t)b * 8 + s) * 256 + j];
        hn[idx] = (1.0f - z) * nn + z * h;
    }
    __syncthreads();

    // ---- LN(mlp) -> A1 rows 0..7 ----
    {
        float4 g4 = *(const float4*)(g_mlp + lane * 4);
        float4 b4 = *(const float4*)(b_mlp + lane * 4);
#pragma unroll
        for (int rep = 0; rep < 2; ++rep) {
            int s = wave * 2 + rep;
            float4 x = *(const float4*)&hn[s * 256 + lane * 4];
            float sm = x.x + x.y + x.z + x.w;
            float sq = x.x * x.x + x.y * x.y + x.z * x.z + x.w * x.w;
#pragma unroll
            for (int off = 32; off > 0; off >>= 1) {
                sm += __shfl_xor(sm, off, 64);
                sq += __shfl_xor(sq, off, 64);
            }
            float mean = sm * (1.0f / 256.0f);
            float rstd = rsqrtf(sq * (1.0f / 256.0f) - mean * mean + 1e-3f);
            uint2 o;
            o.x = (uint32_t)f2bf((x.x - mean) * rstd * g4.x + b4.x) |
                  ((uint32_t)f2bf((x.y - mean) * rstd * g4.y + b4.y) << 16);
            o.y = (uint32_t)f2bf((x.z - mean) * rstd * g4.z + b4.z) |
                  ((uint32_t)f2bf((x.w - mean) * rstd * g4.w + b4.w) << 16);
            *(uint2*)&A1[s * 264 + lane * 4] = o;
        }
    }
    __syncthreads();

    // ---- MLP1: hidden[8x512] = relu(A1 @ W1^T + b1) -> A2 ----
    {
        bf16x8 af[8];
#pragma unroll
        for (int ks = 0; ks < 8; ++ks)
            af[ks] = *(const bf16x8*)&A1[(lane & 15) * 264 + ks * 32 + (lane >> 4) * 8];
#pragma unroll
        for (int nt = 0; nt < 8; ++nt) {
            int n0 = (wave * 8 + nt) * 16;
            f32x4 acc = {0.f, 0.f, 0.f, 0.f};
#pragma unroll
            for (int ks = 0; ks < 8; ++ks) {
                bf16x8 bf = *(const bf16x8*)(W1b + (size_t)(n0 + (lane & 15)) * 256 +
                                             ks * 32 + (lane >> 4) * 8);
                acc = __builtin_amdgcn_mfma_f32_16x16x32_bf16(af[ks], bf, acc, 0, 0, 0);
            }
            int col = n0 + (lane & 15);
            float bs = b1[col];
#pragma unroll
            for (int r = 0; r < 4; ++r) {
                int row = (lane >> 4) * 4 + r;
                if (row < 8) A2[row * 520 + col] = f2bf(fmaxf(acc[r] + bs, 0.f));
            }
        }
    }
    __syncthreads();

    // ---- MLP2: sn = A2 @ W2^T + b2 + hn; write new slots ----
    {
        bf16x8 af[16];
#pragma unroll
        for (int ks = 0; ks < 16; ++ks)
            af[ks] = *(const bf16x8*)&A2[(lane & 15) * 520 + ks * 32 + (lane >> 4) * 8];
#pragma unroll
        for (int nt = 0; nt < 4; ++nt) {
            int n0 = (wave * 4 + nt) * 16;
            f32x4 acc = {0.f, 0.f, 0.f, 0.f};
#pragma unroll
            for (int ks = 0; ks < 16; ++ks) {
                bf16x8 bf = *(const bf16x8*)(W2b + (size_t)(n0 + (lane & 15)) * 512 +
                                             ks * 32 + (lane >> 4) * 8);
                acc = __builtin_amdgcn_mfma_f32_16x16x32_bf16(af[ks], bf, acc, 0, 0, 0);
            }
            int col = n0 + (lane & 15);
            float bs = b2[col];
#pragma unroll
            for (int r = 0; r < 4; ++r) {
                int row = (lane >> 4) * 4 + r;
                if (row < 8) {
                    float v = acc[r] + bs + hn[row * 256 + col];
                    sn[row * 256 + col] = v;
                    slots_out[((size_t)b * 8 + row) * 256 + col] = v;
                }
            }
        }
    }
    if (!do_q) return;
    __syncthreads();

    // ---- LN(slot) on sn -> A1 ----
    {
        float4 g4 = *(const float4*)(g_slot + lane * 4);
        float4 b4 = *(const float4*)(b_slot + lane * 4);
#pragma unroll
        for (int rep = 0; rep < 2; ++rep) {
            int s = wave * 2 + rep;
            float4 x = *(const float4*)&sn[s * 256 + lane * 4];
            float sm = x.x + x.y + x.z + x.w;
            float sq = x.x * x.x + x.y * x.y + x.z * x.z + x.w * x.w;
#pragma unroll
            for (int off = 32; off > 0; off >>= 1) {
                sm += __shfl_xor(sm, off, 64);
                sq += __shfl_xor(sq, off, 64);
            }
            float mean = sm * (1.0f / 256.0f);
            float rstd = rsqrtf(sq * (1.0f / 256.0f) - mean * mean + 1e-3f);
            uint2 o;
            o.x = (uint32_t)f2bf((x.x - mean) * rstd * g4.x + b4.x) |
                  ((uint32_t)f2bf((x.y - mean) * rstd * g4.y + b4.y) << 16);
            o.y = (uint32_t)f2bf((x.z - mean) * rstd * g4.z + b4.z) |
                  ((uint32_t)f2bf((x.w - mean) * rstd * g4.w + b4.w) << 16);
            *(uint2*)&A1[s * 264 + lane * 4] = o;
        }
    }
    __syncthreads();

    // ---- q = A1 @ Wq^T + bq -> qbuf bf16 ----
    {
        bf16x8 af[8];
#pragma unroll
        for (int ks = 0; ks < 8; ++ks)
            af[ks] = *(const bf16x8*)&A1[(lane & 15) * 264 + ks * 32 + (lane >> 4) * 8];
#pragma unroll
        for (int nt = 0; nt < 4; ++nt) {
            int n0 = (wave * 4 + nt) * 16;
            f32x4 acc = {0.f, 0.f, 0.f, 0.f};
#pragma unroll
            for (int ks = 0; ks < 8; ++ks) {
                bf16x8 bf = *(const bf16x8*)(Wqb + (size_t)(n0 + (lane & 15)) * 256 +
                                             ks * 32 + (lane >> 4) * 8);
                acc = __builtin_amdgcn_mfma_f32_16x16x32_bf16(af[ks], bf, acc, 0, 0, 0);
            }
            int col = n0 + (lane & 15);
            float bs = bq[col];
#pragma unroll
            for (int r = 0; r < 4; ++r) {
                int row = (lane >> 4) * 4 + r;
                if (row < 8)
                    qbuf[((size_t)b * 8 + row) * 256 + col] = f2bf(acc[r] + bs);
            }
        }
    }
}

// ---------------------------------------------------------------------------
extern "C" void kernel_launch(void* const* d_in, const int* in_sizes, int n_in,
                              void* d_out, int out_size, void* d_ws, size_t ws_size,
                              hipStream_t stream) {
    const float* inputs    = (const float*)d_in[0];
    const float* slots_in  = (const float*)d_in[1];
    const float* ln_in_g   = (const float*)d_in[3];
    const float* ln_in_b   = (const float*)d_in[4];
    const float* ln_slot_g = (const float*)d_in[5];
    const float* ln_slot_b = (const float*)d_in[6];
    const float* ln_mlp_g  = (const float*)d_in[7];
    const float* ln_mlp_b  = (const float*)d_in[8];
    const float* Wq   = (const float*)d_in[9];
    const float* bq   = (const float*)d_in[10];
    const float* Wk   = (const float*)d_in[11];
    const float* bk   = (const float*)d_in[12];
    const float* Wv   = (const float*)d_in[13];
    const float* bv   = (const float*)d_in[14];
    const float* W_ih = (const float*)d_in[15];
    const float* b_ih = (const float*)d_in[16];
    const float* W_hh = (const float*)d_in[17];
    const float* b_hh = (const float*)d_in[18];
    const float* W1   = (const float*)d_in[19];
    const float* b1   = (const float*)d_in[20];
    const float* W2   = (const float*)d_in[21];
    const float* b2   = (const float*)d_in[22];

    char* p = (char*)d_ws;
    size_t off = 0;
    auto take = [&](size_t bytes) -> char* {
        char* r = p + off;
        off += (bytes + 255) & ~(size_t)255;
        return r;
    };
    unsigned short* Kb   = (unsigned short*)take((size_t)131072 * 256 * 2);
    unsigned short* Vb   = (unsigned short*)take((size_t)131072 * 256 * 2);
    unsigned short* Wkv  = (unsigned short*)take(131072 * 2);
    unsigned short* Wg   = (unsigned short*)take(393216 * 2);
    unsigned short* W1b  = (unsigned short*)take(131072 * 2);
    unsigned short* W2b  = (unsigned short*)take(131072 * 2);
    unsigned short* Wqb  = (unsigned short*)take(65536 * 2);
    float* bkv   = (float*)take(512 * 4);
    float* bg    = (float*)take(1536 * 4);
    unsigned short* qbuf = (unsigned short*)take(65536 * 2);
    float* upd   = (float*)take(65536 * 4 + 256 * 4);   // upd + sums contiguous
    float* sums  = upd + 65536;
    float* gates = (float*)take((size_t)256 * 1536 * 4);
    float* sA    = (float*)take(65536 * 4);
    float* sB    = (float*)take(65536 * 4);

    cvt_all<<<3328, 256, 0, stream>>>(Wk, Wv, W_ih, W_hh, W1, W2, Wq,
                                      bk, bv, b_ih, b_hh,
                                      Wkv, Wg, W1b, W2b, Wqb, bkv, bg);
    lngemm_kv<<<1024, 512, 0, stream>>>(inputs, ln_in_g, ln_in_b, Wkv, bkv, Kb, Vb);
    mfma_gemm_ln<<<dim3(2, 2), 256, 0, stream>>>(slots_in, ln_slot_g, ln_slot_b,
                                                 Wqb, bq, qbuf);

    const float* cur = slots_in;
    float* nxt[3] = {sA, sB, (float*)d_out};
    for (int it = 0; it < 3; ++it) {
        hipMemsetAsync(upd, 0, (65536 + 256) * 4, stream);
        attn_fused<<<dim3(32, 8), 256, 0, stream>>>(qbuf, Kb, Vb, upd, sums);
        slot_gates<<<dim3(2, 12), 256, 0, stream>>>(upd, sums, cur, Wg, bg, gates);
        slot_tail<<<32, 256, 0, stream>>>(gates, cur, ln_mlp_g, ln_mlp_b,
                                          W1b, b1, W2b, b2,
                                          ln_slot_g, ln_slot_b, Wqb, bq,
                                          nxt[it], qbuf, it < 2 ? 1 : 0);
        cur = nxt[it];
    }
    (void)in_sizes; (void)n_in; (void)out_size; (void)ws_size;
}